// Round 14
// baseline (571.619 us; speedup 1.0000x reference)
//
#include <hip/hip_runtime.h>
#include <math.h>

#define N_NODES 100000
#define N_EDGES 1600000
#define NB 64
#define F_IN 128
#define HDIM 64
#define NC 10

#define BSHIFT 9
#define BUCKET_NODES (1 << BSHIFT)                          // 512
#define NBUCK ((N_NODES + BUCKET_NODES - 1) >> BSHIFT)      // 196
#define EW_CHUNK 4096
#define EW_GRID ((N_EDGES + EW_CHUNK - 1) / EW_CHUNK)       // 391

typedef __attribute__((ext_vector_type(8))) short bf16x8;
typedef __attribute__((ext_vector_type(4))) float f32x4;

// ---------- bf16 helpers ----------
__device__ __forceinline__ unsigned short f2bf(float f) {
    unsigned u = __float_as_uint(f);
    u += 0x7FFFu + ((u >> 16) & 1u);    // round to nearest even
    return (unsigned short)(u >> 16);
}
__device__ __forceinline__ float bf2f(unsigned short b) {
    return __uint_as_float((unsigned)b << 16);
}

// ---------- W split: W -> bf16 hi + bf16 lo (residual) ----------
__global__ __launch_bounds__(256) void wsplit(
    const float* __restrict__ W0, const float* __restrict__ W1,
    const float* __restrict__ W2, const float* __restrict__ W3,
    unsigned short* __restrict__ hi, unsigned short* __restrict__ lo, int n)
{
    int i = blockIdx.x * 256 + threadIdx.x;
    if (i >= 4 * n) return;
    const float* Ws[4] = {W0, W1, W2, W3};
    float w = Ws[i / n][i % n];
    unsigned short h = f2bf(w);
    hi[i] = h;
    lo[i] = f2bf(w - bf2f(h));
}

// ---------- fused q/k/v/skip GEMM via MFMA (bf16 3-term residual) ----------
// Wave = 16 rows (one 16x16 row-tile). Grid doubled vs r13 to lift
// occupancy 3->6 waves/SIMD (r13 was grid-capped at 3.05, 90% latency-stall).
// out = Xhi*Whi + Xlo*Whi + Xhi*Wlo  (fp32 MFMA accumulate).
template<int K>
__global__ __launch_bounds__(256) void qkvs_gemm_mfma(
    const float* __restrict__ xin,
    const unsigned short* __restrict__ whi,
    const unsigned short* __restrict__ wlo,
    const float* __restrict__ bq, const float* __restrict__ bk,
    const float* __restrict__ bv, const float* __restrict__ bs,
    float* __restrict__ q, unsigned short* __restrict__ k16,
    unsigned short* __restrict__ v16, float* __restrict__ sk)
{
    constexpr int NCH = K / 32;
    const int tid = threadIdx.x;
    const int wv  = tid >> 6;
    const int l   = tid & 63;
    const int lr  = l & 15;      // A-row / B-col / D-col within tile
    const int lg  = l >> 4;      // k-group (8 consecutive k) ; D-row group
    const int row0 = blockIdx.x * 64 + wv * 16;

    // ---- load X rows, split into bf16 hi/lo fragments ----
    bf16x8 Ahi[NCH], Alo[NCH];
    {
        int row = row0 + lr;
        bool ok = row < N_NODES;
        const float* xr = xin + (size_t)(ok ? row : 0) * K + lg * 8;
        #pragma unroll
        for (int c = 0; c < NCH; c++) {
            float4 f0, f1;
            if (ok) {
                f0 = *(const float4*)(xr + c * 32);
                f1 = *(const float4*)(xr + c * 32 + 4);
            } else {
                f0 = make_float4(0.f, 0.f, 0.f, 0.f);
                f1 = f0;
            }
            float xv[8] = {f0.x, f0.y, f0.z, f0.w, f1.x, f1.y, f1.z, f1.w};
            #pragma unroll
            for (int j = 0; j < 8; j++) {
                unsigned short hb = f2bf(xv[j]);
                Ahi[c][j] = (short)hb;
                Alo[c][j] = (short)f2bf(xv[j] - bf2f(hb));
            }
        }
    }

    const float* Bm[4] = {bq, bk, bv, bs};

    for (int mat = 0; mat < 4; mat++) {
        #pragma unroll
        for (int ct = 0; ct < 4; ct++) {
            const size_t wbase = (size_t)(mat * 64 + ct * 16 + lr) * K + lg * 8;
            f32x4 acc = {0.f, 0.f, 0.f, 0.f};
            #pragma unroll
            for (int c = 0; c < NCH; c++) {
                bf16x8 Bhi = *(const bf16x8*)&whi[wbase + c * 32];
                bf16x8 Blo = *(const bf16x8*)&wlo[wbase + c * 32];
                acc = __builtin_amdgcn_mfma_f32_16x16x32_bf16(Ahi[c], Bhi, acc, 0, 0, 0);
                acc = __builtin_amdgcn_mfma_f32_16x16x32_bf16(Alo[c], Bhi, acc, 0, 0, 0);
                acc = __builtin_amdgcn_mfma_f32_16x16x32_bf16(Ahi[c], Blo, acc, 0, 0, 0);
            }
            float bias = Bm[mat][ct * 16 + lr];
            int colo = ct * 16 + lr;
            // D layout: row = lg*4 + i, col = lr (within tile)
            #pragma unroll
            for (int i = 0; i < 4; i++) {
                int row = row0 + lg * 4 + i;
                if (row < N_NODES) {
                    float val = acc[i] + bias;
                    size_t off = (size_t)row * HDIM + colo;
                    if (mat == 0)      q[off]   = val;
                    else if (mat == 1) k16[off] = f2bf(val);
                    else if (mat == 2) v16[off] = f2bf(val);
                    else               sk[off]  = val;
                }
            }
        }
    }
}

// ---------- CSR build, stage 1: per-bucket edge counts (LDS hist only) ----------
__global__ __launch_bounds__(256) void count_bucket(
    const int* __restrict__ ei, int* __restrict__ bcnt)
{
    __shared__ int hist[NBUCK];
    for (int i = threadIdx.x; i < NBUCK; i += 256) hist[i] = 0;
    __syncthreads();
    int e0 = blockIdx.x * EW_CHUNK;
    #pragma unroll
    for (int i = 0; i < EW_CHUNK / 256; i++) {
        int e = e0 + i * 256 + threadIdx.x;
        if (e < N_EDGES) atomicAdd(&hist[ei[N_EDGES + e] >> BSHIFT], 1);
    }
    __syncthreads();
    for (int i = threadIdx.x; i < NBUCK; i += 256)
        if (hist[i]) atomicAdd(&bcnt[i], hist[i]);
}

// ---------- CSR build, stage 2: bucket base scan (196 values, one block) ----------
__global__ __launch_bounds__(256) void scan_bucket(
    const int* __restrict__ bcnt, int* __restrict__ bbase, int* __restrict__ gcursor)
{
    __shared__ int sh[256];
    int t = threadIdx.x;
    int v = (t < NBUCK) ? bcnt[t] : 0;
    sh[t] = v;
    __syncthreads();
    for (int off = 1; off < 256; off <<= 1) {
        int u = (t >= off) ? sh[t - off] : 0;
        __syncthreads();
        sh[t] += u;
        __syncthreads();
    }
    if (t < NBUCK) { bbase[t] = sh[t] - v; gcursor[t] = sh[t] - v; }
}

// ---------- CSR build, stage 3: scatter packed edges into bucket order ----------
// packed entry: (dst_local << 17) | src
__global__ __launch_bounds__(256) void bucket_scatter(
    const int* __restrict__ ei, int* __restrict__ gcursor, int* __restrict__ bedge)
{
    __shared__ int hist[NBUCK];
    __shared__ int base[NBUCK];
    for (int i = threadIdx.x; i < NBUCK; i += 256) hist[i] = 0;
    __syncthreads();
    int e0 = blockIdx.x * EW_CHUNK;
    #pragma unroll
    for (int i = 0; i < EW_CHUNK / 256; i++) {
        int e = e0 + i * 256 + threadIdx.x;
        if (e < N_EDGES) atomicAdd(&hist[ei[N_EDGES + e] >> BSHIFT], 1);
    }
    __syncthreads();
    for (int i = threadIdx.x; i < NBUCK; i += 256)
        base[i] = hist[i] ? atomicAdd(&gcursor[i], hist[i]) : 0;
    __syncthreads();
    for (int i = threadIdx.x; i < NBUCK; i += 256) hist[i] = 0;
    __syncthreads();
    #pragma unroll
    for (int i = 0; i < EW_CHUNK / 256; i++) {
        int e = e0 + i * 256 + threadIdx.x;
        if (e < N_EDGES) {
            int src = ei[e];
            int dst = ei[N_EDGES + e];
            int b = dst >> BSHIFT;
            int pos = base[b] + atomicAdd(&hist[b], 1);
            bedge[pos] = ((dst & (BUCKET_NODES - 1)) << 17) | src;
        }
    }
}

// ---------- CSR build, stage 4: one WG per bucket ----------
__global__ __launch_bounds__(256) void csr_from_buckets(
    const int* __restrict__ bedge, const int* __restrict__ bbase,
    const int* __restrict__ bcnt, int* __restrict__ row_ptr,
    int* __restrict__ csr_src)
{
    __shared__ int cur[BUCKET_NODES];   // 512
    __shared__ int psum[256];
    const int b = blockIdx.x;
    const int dst0 = b << BSHIFT;
    const int t = threadIdx.x;

    for (int i = t; i < BUCKET_NODES; i += 256) cur[i] = 0;
    __syncthreads();

    const int beg = bbase[b], cnt = bcnt[b];
    for (int i = t; i < cnt; i += 256)
        atomicAdd(&cur[bedge[beg + i] >> 17], 1);
    __syncthreads();

    int a0 = cur[2 * t], a1 = cur[2 * t + 1];
    int pair = a0 + a1;
    psum[t] = pair;
    __syncthreads();
    for (int off = 1; off < 256; off <<= 1) {
        int u = (t >= off) ? psum[t - off] : 0;
        __syncthreads();
        psum[t] += u;
        __syncthreads();
    }
    int ex = psum[t] - pair;            // exclusive prefix of this pair

    int d0 = dst0 + 2 * t, d1 = d0 + 1;
    int g0 = beg + ex, g1 = beg + ex + a0;
    if (d0 < N_NODES) row_ptr[d0] = g0;
    if (d1 < N_NODES) row_ptr[d1] = g1;
    if (b == gridDim.x - 1 && t == 255) row_ptr[N_NODES] = beg + psum[255];
    cur[2 * t] = g0;
    cur[2 * t + 1] = g1;
    __syncthreads();

    for (int i = t; i < cnt; i += 256) {
        int ed = bedge[beg + i];
        int pos = atomicAdd(&cur[ed >> 17], 1);
        csr_src[pos] = ed & 0x1FFFF;
    }
}

// ---------- fused attention: wave per dst, 8 edges/iter, bf16 k/v gathers ----------
__global__ __launch_bounds__(256) void attn_fused(
    const int* __restrict__ row_ptr, const int* __restrict__ csr_src,
    const float* __restrict__ q, const unsigned short* __restrict__ k16,
    const unsigned short* __restrict__ v16, const float* __restrict__ skip,
    float* __restrict__ hout, int do_relu)
{
    int n = blockIdx.x * 4 + (threadIdx.x >> 6);
    if (n >= N_NODES) return;
    int lane = threadIdx.x & 63;
    int g = lane >> 3;
    int t = lane & 7;
    int beg = row_ptr[n], end = row_ptr[n + 1];

    const float* qrow = &q[(size_t)n * HDIM + t * 8];
    float4 qa = *(const float4*)qrow;
    float4 qb = *(const float4*)(qrow + 4);
    float m = -1e30f, s = 0.f;
    float4 aca = make_float4(0.f, 0.f, 0.f, 0.f);
    float4 acb = make_float4(0.f, 0.f, 0.f, 0.f);

    for (int i = beg; i < end; i += 8) {
        int e = i + g;
        bool valid = (e < end);
        int src = csr_src[valid ? e : beg];
        uint4 ku = *(const uint4*)&k16[(size_t)src * HDIM + t * 8];
        uint4 vu = *(const uint4*)&v16[(size_t)src * HDIM + t * 8];
        float p = qa.x * __uint_as_float(ku.x << 16)
                + qa.y * __uint_as_float(ku.x & 0xFFFF0000u)
                + qa.z * __uint_as_float(ku.y << 16)
                + qa.w * __uint_as_float(ku.y & 0xFFFF0000u)
                + qb.x * __uint_as_float(ku.z << 16)
                + qb.y * __uint_as_float(ku.z & 0xFFFF0000u)
                + qb.z * __uint_as_float(ku.w << 16)
                + qb.w * __uint_as_float(ku.w & 0xFFFF0000u);
        p += __shfl_xor(p, 1, 64);
        p += __shfl_xor(p, 2, 64);
        p += __shfl_xor(p, 4, 64);
        float a = valid ? p * 0.125f : -INFINITY;
        float mn = fmaxf(m, a);
        float sc = __expf(m - mn);
        float ew = __expf(a - mn);
        s = s * sc + ew;
        aca.x = aca.x * sc + ew * __uint_as_float(vu.x << 16);
        aca.y = aca.y * sc + ew * __uint_as_float(vu.x & 0xFFFF0000u);
        aca.z = aca.z * sc + ew * __uint_as_float(vu.y << 16);
        aca.w = aca.w * sc + ew * __uint_as_float(vu.y & 0xFFFF0000u);
        acb.x = acb.x * sc + ew * __uint_as_float(vu.z << 16);
        acb.y = acb.y * sc + ew * __uint_as_float(vu.z & 0xFFFF0000u);
        acb.z = acb.z * sc + ew * __uint_as_float(vu.w << 16);
        acb.w = acb.w * sc + ew * __uint_as_float(vu.w & 0xFFFF0000u);
        m = mn;
    }

    #pragma unroll
    for (int off = 8; off <= 32; off <<= 1) {
        float m2 = __shfl_xor(m, off, 64);
        float s2 = __shfl_xor(s, off, 64);
        float x0 = __shfl_xor(aca.x, off, 64);
        float x1 = __shfl_xor(aca.y, off, 64);
        float x2 = __shfl_xor(aca.z, off, 64);
        float x3 = __shfl_xor(aca.w, off, 64);
        float x4 = __shfl_xor(acb.x, off, 64);
        float x5 = __shfl_xor(acb.y, off, 64);
        float x6 = __shfl_xor(acb.z, off, 64);
        float x7 = __shfl_xor(acb.w, off, 64);
        float mn = fmaxf(m, m2);
        float c1 = __expf(m - mn);
        float c2 = __expf(m2 - mn);
        s = s * c1 + s2 * c2;
        aca.x = aca.x * c1 + x0 * c2;
        aca.y = aca.y * c1 + x1 * c2;
        aca.z = aca.z * c1 + x2 * c2;
        aca.w = aca.w * c1 + x3 * c2;
        acb.x = acb.x * c1 + x4 * c2;
        acb.y = acb.y * c1 + x5 * c2;
        acb.z = acb.z * c1 + x6 * c2;
        acb.w = acb.w * c1 + x7 * c2;
        m = mn;
    }

    if (g == 0) {
        float inv = (s > 0.f) ? (1.f / s) : 0.f;
        const float* skrow = &skip[(size_t)n * HDIM + t * 8];
        float4 s0 = *(const float4*)skrow;
        float4 s1 = *(const float4*)(skrow + 4);
        float4 o0, o1;
        o0.x = aca.x * inv + s0.x;
        o0.y = aca.y * inv + s0.y;
        o0.z = aca.z * inv + s0.z;
        o0.w = aca.w * inv + s0.w;
        o1.x = acb.x * inv + s1.x;
        o1.y = acb.y * inv + s1.y;
        o1.z = acb.z * inv + s1.z;
        o1.w = acb.w * inv + s1.w;
        if (do_relu) {
            o0.x = fmaxf(o0.x, 0.f); o0.y = fmaxf(o0.y, 0.f);
            o0.z = fmaxf(o0.z, 0.f); o0.w = fmaxf(o0.w, 0.f);
            o1.x = fmaxf(o1.x, 0.f); o1.y = fmaxf(o1.y, 0.f);
            o1.z = fmaxf(o1.z, 0.f); o1.w = fmaxf(o1.w, 0.f);
        }
        float* orow = &hout[(size_t)n * HDIM + t * 8];
        *(float4*)orow = o0;
        *(float4*)(orow + 4) = o1;
    }
}

// ---------- mean pool: run-length accumulate (batch sorted) ----------
__global__ __launch_bounds__(256) void pool_kernel(
    const float* __restrict__ h, const int* __restrict__ batch,
    float* __restrict__ sums, float* __restrict__ cnt)
{
    int wid = blockIdx.x * 4 + (threadIdx.x >> 6);
    int n0 = wid * 64;
    if (n0 >= N_NODES) return;
    int lane = threadIdx.x & 63;
    int nend = min(n0 + 64, N_NODES);
    float acc = 0.f;
    int b_cur = batch[n0];
    int run = 0;
    for (int n = n0; n < nend; n++) {
        int b = batch[n];
        if (b != b_cur) {
            atomicAdd(&sums[b_cur * HDIM + lane], acc);
            if (lane == 0) atomicAdd(&cnt[b_cur], (float)run);
            acc = 0.f; run = 0; b_cur = b;
        }
        acc += h[(size_t)n * HDIM + lane];
        run++;
    }
    atomicAdd(&sums[b_cur * HDIM + lane], acc);
    if (lane == 0) atomicAdd(&cnt[b_cur], (float)run);
}

// ---------- head ----------
__global__ void head_kernel(
    const float* __restrict__ sums, const float* __restrict__ cnt,
    const float* __restrict__ Wl, const float* __restrict__ bl,
    float* __restrict__ out)
{
    int tid = threadIdx.x;
    if (tid >= NB * NC) return;
    int b = tid / NC, c = tid % NC;
    float cc = fmaxf(cnt[b], 1.0f);
    float acc = bl[c];
    #pragma unroll
    for (int f = 0; f < HDIM; f++)
        acc += (sums[b * HDIM + f] / cc) * Wl[c * HDIM + f];
    out[tid] = acc;
}

extern "C" void kernel_launch(void* const* d_in, const int* in_sizes, int n_in,
                              void* d_out, int out_size, void* d_ws, size_t ws_size,
                              hipStream_t stream)
{
    const float* x     = (const float*)d_in[0];
    const int*   ei    = (const int*)d_in[1];
    const int*   batch = (const int*)d_in[2];

    const float* W[3][4];
    const float* B[3][4];
    for (int l = 0; l < 3; l++)
        for (int j = 0; j < 4; j++) {
            W[l][j] = (const float*)d_in[3 + l * 8 + j * 2];
            B[l][j] = (const float*)d_in[3 + l * 8 + j * 2 + 1];
        }
    const float* Wl = (const float*)d_in[27];
    const float* bl = (const float*)d_in[28];
    float* out = (float*)d_out;

    const size_t NF = (size_t)N_NODES * HDIM;
    char* w = (char*)d_ws;
    float*          h       = (float*)w;          w += NF * 4;
    float*          q       = (float*)w;          w += NF * 4;
    unsigned short* k16     = (unsigned short*)w; w += NF * 2;
    unsigned short* v16     = (unsigned short*)w; w += NF * 2;
    float*          skip    = (float*)w;          w += NF * 4;
    int*            csr_src = (int*)w;            w += (size_t)N_EDGES * 4;
    int*            bedge   = (int*)w;            w += (size_t)N_EDGES * 4;
    int*            row_ptr = (int*)w;            w += (size_t)(N_NODES + 1) * 4;
    int*            bcnt    = (int*)w;            w += (size_t)NBUCK * 4;
    int*            bbase   = (int*)w;            w += (size_t)NBUCK * 4;
    int*            gcursor = (int*)w;            w += (size_t)NBUCK * 4;
    float*          sums    = (float*)w;          w += (size_t)NB * HDIM * 4;
    float*          cnt     = (float*)w;          w += (size_t)NB * 4;
    unsigned short* whi[3];
    unsigned short* wlo[3];
    const int wsz[3] = {64 * F_IN, 64 * HDIM, 64 * HDIM};   // per-mat elems
    for (int l = 0; l < 3; l++) {
        whi[l] = (unsigned short*)w; w += (size_t)4 * wsz[l] * 2;
        wlo[l] = (unsigned short*)w; w += (size_t)4 * wsz[l] * 2;
    }

    const int gemm_gx = (N_NODES + 63) / 64;
    const int node_gx = (N_NODES + 3) / 4;
    const int pool_gx = (N_NODES + 64 * 4 - 1) / (64 * 4);

    // ----- W split to bf16 hi/lo (once) -----
    for (int l = 0; l < 3; l++) {
        int n = wsz[l];
        wsplit<<<(4 * n + 255) / 256, 256, 0, stream>>>(
            W[l][0], W[l][1], W[l][2], W[l][3], whi[l], wlo[l], n);
    }

    // ----- CSR build via LDS-staged counting sort (once; shared by all layers) -----
    hipMemsetAsync(bcnt, 0, (size_t)NBUCK * 4, stream);
    count_bucket<<<EW_GRID, 256, 0, stream>>>(ei, bcnt);
    scan_bucket<<<1, 256, 0, stream>>>(bcnt, bbase, gcursor);
    bucket_scatter<<<EW_GRID, 256, 0, stream>>>(ei, gcursor, bedge);
    csr_from_buckets<<<NBUCK, 256, 0, stream>>>(bedge, bbase, bcnt, row_ptr, csr_src);

    for (int l = 0; l < 3; l++) {
        if (l == 0) {
            qkvs_gemm_mfma<F_IN><<<gemm_gx, 256, 0, stream>>>(
                x, whi[0], wlo[0], B[0][0], B[0][1], B[0][2], B[0][3],
                q, k16, v16, skip);
        } else {
            qkvs_gemm_mfma<HDIM><<<gemm_gx, 256, 0, stream>>>(
                h, whi[l], wlo[l], B[l][0], B[l][1], B[l][2], B[l][3],
                q, k16, v16, skip);
        }
        attn_fused<<<node_gx, 256, 0, stream>>>(
            row_ptr, csr_src, q, k16, v16, skip, h, l < 2 ? 1 : 0);
    }

    hipMemsetAsync(sums, 0, (size_t)NB * HDIM * 4, stream);
    hipMemsetAsync(cnt,  0, (size_t)NB * 4, stream);
    pool_kernel<<<pool_gx, 256, 0, stream>>>(h, batch, sums, cnt);
    head_kernel<<<1, 640, 0, stream>>>(sums, cnt, Wl, bl, out);
}

// Round 15
// 488.710 us; speedup vs baseline: 1.1696x; 1.1696x over previous
//
#include <hip/hip_runtime.h>
#include <math.h>

#define N_NODES 100000
#define N_EDGES 1600000
#define NB 64
#define F_IN 128
#define HDIM 64
#define NC 10

#define BSHIFT 9
#define BUCKET_NODES (1 << BSHIFT)                          // 512
#define NBUCK ((N_NODES + BUCKET_NODES - 1) >> BSHIFT)      // 196
#define EW_CHUNK 4096
#define EW_GRID ((N_EDGES + EW_CHUNK - 1) / EW_CHUNK)       // 391

typedef __attribute__((ext_vector_type(8))) short bf16x8;
typedef __attribute__((ext_vector_type(4))) float f32x4;

// ---------- bf16 helpers ----------
__device__ __forceinline__ unsigned short f2bf(float f) {
    unsigned u = __float_as_uint(f);
    u += 0x7FFFu + ((u >> 16) & 1u);    // round to nearest even
    return (unsigned short)(u >> 16);
}
__device__ __forceinline__ float bf2f(unsigned short b) {
    return __uint_as_float((unsigned)b << 16);
}

// ---------- W split: W -> bf16 hi + bf16 lo (residual) ----------
__global__ __launch_bounds__(256) void wsplit(
    const float* __restrict__ W0, const float* __restrict__ W1,
    const float* __restrict__ W2, const float* __restrict__ W3,
    unsigned short* __restrict__ hi, unsigned short* __restrict__ lo, int n)
{
    int i = blockIdx.x * 256 + threadIdx.x;
    if (i >= 4 * n) return;
    const float* Ws[4] = {W0, W1, W2, W3};
    float w = Ws[i / n][i % n];
    unsigned short h = f2bf(w);
    hi[i] = h;
    lo[i] = f2bf(w - bf2f(h));
}

// ---------- fused q/k/v/skip GEMM via MFMA (bf16 3-term residual) ----------
// Wave = 32 rows (2 row-tiles). gridDim.y = 2 splits the 4 mats (2 per block):
// B traffic stays at r13's level (each [rowtile,ct] B-frag loaded once) while
// wave count doubles to ~6.1/SIMD (r14's mistake: halving rows doubled B traffic).
// out = Xhi*Whi + Xlo*Whi + Xhi*Wlo  (fp32 MFMA accumulate).
template<int K>
__global__ __launch_bounds__(256) void qkvs_gemm_mfma(
    const float* __restrict__ xin,
    const unsigned short* __restrict__ whi,
    const unsigned short* __restrict__ wlo,
    const float* __restrict__ bq, const float* __restrict__ bk,
    const float* __restrict__ bv, const float* __restrict__ bs,
    float* __restrict__ q, unsigned short* __restrict__ k16,
    unsigned short* __restrict__ v16, float* __restrict__ sk)
{
    constexpr int NCH = K / 32;
    const int tid = threadIdx.x;
    const int wv  = tid >> 6;
    const int l   = tid & 63;
    const int lr  = l & 15;      // A-row / B-col / D-col within tile
    const int lg  = l >> 4;      // k-group (8 consecutive k) ; D-row group
    const int row0 = blockIdx.x * 128 + wv * 32;
    const int mat0 = blockIdx.y * 2;

    // ---- load X rows, split into bf16 hi/lo fragments ----
    bf16x8 Ahi[2][NCH], Alo[2][NCH];
    #pragma unroll
    for (int rt = 0; rt < 2; rt++) {
        int row = row0 + rt * 16 + lr;
        bool ok = row < N_NODES;
        const float* xr = xin + (size_t)(ok ? row : 0) * K + lg * 8;
        #pragma unroll
        for (int c = 0; c < NCH; c++) {
            float4 f0, f1;
            if (ok) {
                f0 = *(const float4*)(xr + c * 32);
                f1 = *(const float4*)(xr + c * 32 + 4);
            } else {
                f0 = make_float4(0.f, 0.f, 0.f, 0.f);
                f1 = f0;
            }
            float xv[8] = {f0.x, f0.y, f0.z, f0.w, f1.x, f1.y, f1.z, f1.w};
            #pragma unroll
            for (int j = 0; j < 8; j++) {
                unsigned short hb = f2bf(xv[j]);
                Ahi[rt][c][j] = (short)hb;
                Alo[rt][c][j] = (short)f2bf(xv[j] - bf2f(hb));
            }
        }
    }

    const float* Bm[4] = {bq, bk, bv, bs};

    #pragma unroll
    for (int mm = 0; mm < 2; mm++) {
        const int mat = mat0 + mm;
        #pragma unroll
        for (int ct = 0; ct < 4; ct++) {
            const size_t wbase = (size_t)(mat * 64 + ct * 16 + lr) * K + lg * 8;
            f32x4 acc0 = {0.f, 0.f, 0.f, 0.f};
            f32x4 acc1 = {0.f, 0.f, 0.f, 0.f};
            #pragma unroll
            for (int c = 0; c < NCH; c++) {
                bf16x8 Bhi = *(const bf16x8*)&whi[wbase + c * 32];
                bf16x8 Blo = *(const bf16x8*)&wlo[wbase + c * 32];
                acc0 = __builtin_amdgcn_mfma_f32_16x16x32_bf16(Ahi[0][c], Bhi, acc0, 0, 0, 0);
                acc1 = __builtin_amdgcn_mfma_f32_16x16x32_bf16(Ahi[1][c], Bhi, acc1, 0, 0, 0);
                acc0 = __builtin_amdgcn_mfma_f32_16x16x32_bf16(Alo[0][c], Bhi, acc0, 0, 0, 0);
                acc1 = __builtin_amdgcn_mfma_f32_16x16x32_bf16(Alo[1][c], Bhi, acc1, 0, 0, 0);
                acc0 = __builtin_amdgcn_mfma_f32_16x16x32_bf16(Ahi[0][c], Blo, acc0, 0, 0, 0);
                acc1 = __builtin_amdgcn_mfma_f32_16x16x32_bf16(Ahi[1][c], Blo, acc1, 0, 0, 0);
            }
            float bias = Bm[mat][ct * 16 + lr];
            int colo = ct * 16 + lr;
            // D layout: row = rt*16 + lg*4 + i, col = lr (within tile)
            #pragma unroll
            for (int i = 0; i < 4; i++) {
                int row = row0 + lg * 4 + i;
                if (row < N_NODES) {
                    float val = acc0[i] + bias;
                    size_t off = (size_t)row * HDIM + colo;
                    if (mat == 0)      q[off]   = val;
                    else if (mat == 1) k16[off] = f2bf(val);
                    else if (mat == 2) v16[off] = f2bf(val);
                    else               sk[off]  = val;
                }
            }
            #pragma unroll
            for (int i = 0; i < 4; i++) {
                int row = row0 + 16 + lg * 4 + i;
                if (row < N_NODES) {
                    float val = acc1[i] + bias;
                    size_t off = (size_t)row * HDIM + colo;
                    if (mat == 0)      q[off]   = val;
                    else if (mat == 1) k16[off] = f2bf(val);
                    else if (mat == 2) v16[off] = f2bf(val);
                    else               sk[off]  = val;
                }
            }
        }
    }
}

// ---------- CSR build, stage 1: per-bucket edge counts (LDS hist only) ----------
__global__ __launch_bounds__(256) void count_bucket(
    const int* __restrict__ ei, int* __restrict__ bcnt)
{
    __shared__ int hist[NBUCK];
    for (int i = threadIdx.x; i < NBUCK; i += 256) hist[i] = 0;
    __syncthreads();
    int e0 = blockIdx.x * EW_CHUNK;
    #pragma unroll
    for (int i = 0; i < EW_CHUNK / 256; i++) {
        int e = e0 + i * 256 + threadIdx.x;
        if (e < N_EDGES) atomicAdd(&hist[ei[N_EDGES + e] >> BSHIFT], 1);
    }
    __syncthreads();
    for (int i = threadIdx.x; i < NBUCK; i += 256)
        if (hist[i]) atomicAdd(&bcnt[i], hist[i]);
}

// ---------- CSR build, stage 2: bucket base scan (196 values, one block) ----------
__global__ __launch_bounds__(256) void scan_bucket(
    const int* __restrict__ bcnt, int* __restrict__ bbase, int* __restrict__ gcursor)
{
    __shared__ int sh[256];
    int t = threadIdx.x;
    int v = (t < NBUCK) ? bcnt[t] : 0;
    sh[t] = v;
    __syncthreads();
    for (int off = 1; off < 256; off <<= 1) {
        int u = (t >= off) ? sh[t - off] : 0;
        __syncthreads();
        sh[t] += u;
        __syncthreads();
    }
    if (t < NBUCK) { bbase[t] = sh[t] - v; gcursor[t] = sh[t] - v; }
}

// ---------- CSR build, stage 3: scatter packed edges into bucket order ----------
// packed entry: (dst_local << 17) | src
__global__ __launch_bounds__(256) void bucket_scatter(
    const int* __restrict__ ei, int* __restrict__ gcursor, int* __restrict__ bedge)
{
    __shared__ int hist[NBUCK];
    __shared__ int base[NBUCK];
    for (int i = threadIdx.x; i < NBUCK; i += 256) hist[i] = 0;
    __syncthreads();
    int e0 = blockIdx.x * EW_CHUNK;
    #pragma unroll
    for (int i = 0; i < EW_CHUNK / 256; i++) {
        int e = e0 + i * 256 + threadIdx.x;
        if (e < N_EDGES) atomicAdd(&hist[ei[N_EDGES + e] >> BSHIFT], 1);
    }
    __syncthreads();
    for (int i = threadIdx.x; i < NBUCK; i += 256)
        base[i] = hist[i] ? atomicAdd(&gcursor[i], hist[i]) : 0;
    __syncthreads();
    for (int i = threadIdx.x; i < NBUCK; i += 256) hist[i] = 0;
    __syncthreads();
    #pragma unroll
    for (int i = 0; i < EW_CHUNK / 256; i++) {
        int e = e0 + i * 256 + threadIdx.x;
        if (e < N_EDGES) {
            int src = ei[e];
            int dst = ei[N_EDGES + e];
            int b = dst >> BSHIFT;
            int pos = base[b] + atomicAdd(&hist[b], 1);
            bedge[pos] = ((dst & (BUCKET_NODES - 1)) << 17) | src;
        }
    }
}

// ---------- CSR build, stage 4: one WG per bucket ----------
__global__ __launch_bounds__(256) void csr_from_buckets(
    const int* __restrict__ bedge, const int* __restrict__ bbase,
    const int* __restrict__ bcnt, int* __restrict__ row_ptr,
    int* __restrict__ csr_src)
{
    __shared__ int cur[BUCKET_NODES];   // 512
    __shared__ int psum[256];
    const int b = blockIdx.x;
    const int dst0 = b << BSHIFT;
    const int t = threadIdx.x;

    for (int i = t; i < BUCKET_NODES; i += 256) cur[i] = 0;
    __syncthreads();

    const int beg = bbase[b], cnt = bcnt[b];
    for (int i = t; i < cnt; i += 256)
        atomicAdd(&cur[bedge[beg + i] >> 17], 1);
    __syncthreads();

    int a0 = cur[2 * t], a1 = cur[2 * t + 1];
    int pair = a0 + a1;
    psum[t] = pair;
    __syncthreads();
    for (int off = 1; off < 256; off <<= 1) {
        int u = (t >= off) ? psum[t - off] : 0;
        __syncthreads();
        psum[t] += u;
        __syncthreads();
    }
    int ex = psum[t] - pair;            // exclusive prefix of this pair

    int d0 = dst0 + 2 * t, d1 = d0 + 1;
    int g0 = beg + ex, g1 = beg + ex + a0;
    if (d0 < N_NODES) row_ptr[d0] = g0;
    if (d1 < N_NODES) row_ptr[d1] = g1;
    if (b == gridDim.x - 1 && t == 255) row_ptr[N_NODES] = beg + psum[255];
    cur[2 * t] = g0;
    cur[2 * t + 1] = g1;
    __syncthreads();

    for (int i = t; i < cnt; i += 256) {
        int ed = bedge[beg + i];
        int pos = atomicAdd(&cur[ed >> 17], 1);
        csr_src[pos] = ed & 0x1FFFF;
    }
}

// ---------- fused attention: wave per dst, 8 edges/iter, bf16 k/v gathers ----------
__global__ __launch_bounds__(256) void attn_fused(
    const int* __restrict__ row_ptr, const int* __restrict__ csr_src,
    const float* __restrict__ q, const unsigned short* __restrict__ k16,
    const unsigned short* __restrict__ v16, const float* __restrict__ skip,
    float* __restrict__ hout, int do_relu)
{
    int n = blockIdx.x * 4 + (threadIdx.x >> 6);
    if (n >= N_NODES) return;
    int lane = threadIdx.x & 63;
    int g = lane >> 3;
    int t = lane & 7;
    int beg = row_ptr[n], end = row_ptr[n + 1];

    const float* qrow = &q[(size_t)n * HDIM + t * 8];
    float4 qa = *(const float4*)qrow;
    float4 qb = *(const float4*)(qrow + 4);
    float m = -1e30f, s = 0.f;
    float4 aca = make_float4(0.f, 0.f, 0.f, 0.f);
    float4 acb = make_float4(0.f, 0.f, 0.f, 0.f);

    for (int i = beg; i < end; i += 8) {
        int e = i + g;
        bool valid = (e < end);
        int src = csr_src[valid ? e : beg];
        uint4 ku = *(const uint4*)&k16[(size_t)src * HDIM + t * 8];
        uint4 vu = *(const uint4*)&v16[(size_t)src * HDIM + t * 8];
        float p = qa.x * __uint_as_float(ku.x << 16)
                + qa.y * __uint_as_float(ku.x & 0xFFFF0000u)
                + qa.z * __uint_as_float(ku.y << 16)
                + qa.w * __uint_as_float(ku.y & 0xFFFF0000u)
                + qb.x * __uint_as_float(ku.z << 16)
                + qb.y * __uint_as_float(ku.z & 0xFFFF0000u)
                + qb.z * __uint_as_float(ku.w << 16)
                + qb.w * __uint_as_float(ku.w & 0xFFFF0000u);
        p += __shfl_xor(p, 1, 64);
        p += __shfl_xor(p, 2, 64);
        p += __shfl_xor(p, 4, 64);
        float a = valid ? p * 0.125f : -INFINITY;
        float mn = fmaxf(m, a);
        float sc = __expf(m - mn);
        float ew = __expf(a - mn);
        s = s * sc + ew;
        aca.x = aca.x * sc + ew * __uint_as_float(vu.x << 16);
        aca.y = aca.y * sc + ew * __uint_as_float(vu.x & 0xFFFF0000u);
        aca.z = aca.z * sc + ew * __uint_as_float(vu.y << 16);
        aca.w = aca.w * sc + ew * __uint_as_float(vu.y & 0xFFFF0000u);
        acb.x = acb.x * sc + ew * __uint_as_float(vu.z << 16);
        acb.y = acb.y * sc + ew * __uint_as_float(vu.z & 0xFFFF0000u);
        acb.z = acb.z * sc + ew * __uint_as_float(vu.w << 16);
        acb.w = acb.w * sc + ew * __uint_as_float(vu.w & 0xFFFF0000u);
        m = mn;
    }

    #pragma unroll
    for (int off = 8; off <= 32; off <<= 1) {
        float m2 = __shfl_xor(m, off, 64);
        float s2 = __shfl_xor(s, off, 64);
        float x0 = __shfl_xor(aca.x, off, 64);
        float x1 = __shfl_xor(aca.y, off, 64);
        float x2 = __shfl_xor(aca.z, off, 64);
        float x3 = __shfl_xor(aca.w, off, 64);
        float x4 = __shfl_xor(acb.x, off, 64);
        float x5 = __shfl_xor(acb.y, off, 64);
        float x6 = __shfl_xor(acb.z, off, 64);
        float x7 = __shfl_xor(acb.w, off, 64);
        float mn = fmaxf(m, m2);
        float c1 = __expf(m - mn);
        float c2 = __expf(m2 - mn);
        s = s * c1 + s2 * c2;
        aca.x = aca.x * c1 + x0 * c2;
        aca.y = aca.y * c1 + x1 * c2;
        aca.z = aca.z * c1 + x2 * c2;
        aca.w = aca.w * c1 + x3 * c2;
        acb.x = acb.x * c1 + x4 * c2;
        acb.y = acb.y * c1 + x5 * c2;
        acb.z = acb.z * c1 + x6 * c2;
        acb.w = acb.w * c1 + x7 * c2;
        m = mn;
    }

    if (g == 0) {
        float inv = (s > 0.f) ? (1.f / s) : 0.f;
        const float* skrow = &skip[(size_t)n * HDIM + t * 8];
        float4 s0 = *(const float4*)skrow;
        float4 s1 = *(const float4*)(skrow + 4);
        float4 o0, o1;
        o0.x = aca.x * inv + s0.x;
        o0.y = aca.y * inv + s0.y;
        o0.z = aca.z * inv + s0.z;
        o0.w = aca.w * inv + s0.w;
        o1.x = acb.x * inv + s1.x;
        o1.y = acb.y * inv + s1.y;
        o1.z = acb.z * inv + s1.z;
        o1.w = acb.w * inv + s1.w;
        if (do_relu) {
            o0.x = fmaxf(o0.x, 0.f); o0.y = fmaxf(o0.y, 0.f);
            o0.z = fmaxf(o0.z, 0.f); o0.w = fmaxf(o0.w, 0.f);
            o1.x = fmaxf(o1.x, 0.f); o1.y = fmaxf(o1.y, 0.f);
            o1.z = fmaxf(o1.z, 0.f); o1.w = fmaxf(o1.w, 0.f);
        }
        float* orow = &hout[(size_t)n * HDIM + t * 8];
        *(float4*)orow = o0;
        *(float4*)(orow + 4) = o1;
    }
}

// ---------- mean pool: run-length accumulate (batch sorted) ----------
__global__ __launch_bounds__(256) void pool_kernel(
    const float* __restrict__ h, const int* __restrict__ batch,
    float* __restrict__ sums, float* __restrict__ cnt)
{
    int wid = blockIdx.x * 4 + (threadIdx.x >> 6);
    int n0 = wid * 64;
    if (n0 >= N_NODES) return;
    int lane = threadIdx.x & 63;
    int nend = min(n0 + 64, N_NODES);
    float acc = 0.f;
    int b_cur = batch[n0];
    int run = 0;
    for (int n = n0; n < nend; n++) {
        int b = batch[n];
        if (b != b_cur) {
            atomicAdd(&sums[b_cur * HDIM + lane], acc);
            if (lane == 0) atomicAdd(&cnt[b_cur], (float)run);
            acc = 0.f; run = 0; b_cur = b;
        }
        acc += h[(size_t)n * HDIM + lane];
        run++;
    }
    atomicAdd(&sums[b_cur * HDIM + lane], acc);
    if (lane == 0) atomicAdd(&cnt[b_cur], (float)run);
}

// ---------- head ----------
__global__ void head_kernel(
    const float* __restrict__ sums, const float* __restrict__ cnt,
    const float* __restrict__ Wl, const float* __restrict__ bl,
    float* __restrict__ out)
{
    int tid = threadIdx.x;
    if (tid >= NB * NC) return;
    int b = tid / NC, c = tid % NC;
    float cc = fmaxf(cnt[b], 1.0f);
    float acc = bl[c];
    #pragma unroll
    for (int f = 0; f < HDIM; f++)
        acc += (sums[b * HDIM + f] / cc) * Wl[c * HDIM + f];
    out[tid] = acc;
}

extern "C" void kernel_launch(void* const* d_in, const int* in_sizes, int n_in,
                              void* d_out, int out_size, void* d_ws, size_t ws_size,
                              hipStream_t stream)
{
    const float* x     = (const float*)d_in[0];
    const int*   ei    = (const int*)d_in[1];
    const int*   batch = (const int*)d_in[2];

    const float* W[3][4];
    const float* B[3][4];
    for (int l = 0; l < 3; l++)
        for (int j = 0; j < 4; j++) {
            W[l][j] = (const float*)d_in[3 + l * 8 + j * 2];
            B[l][j] = (const float*)d_in[3 + l * 8 + j * 2 + 1];
        }
    const float* Wl = (const float*)d_in[27];
    const float* bl = (const float*)d_in[28];
    float* out = (float*)d_out;

    const size_t NF = (size_t)N_NODES * HDIM;
    char* w = (char*)d_ws;
    float*          h       = (float*)w;          w += NF * 4;
    float*          q       = (float*)w;          w += NF * 4;
    unsigned short* k16     = (unsigned short*)w; w += NF * 2;
    unsigned short* v16     = (unsigned short*)w; w += NF * 2;
    float*          skip    = (float*)w;          w += NF * 4;
    int*            csr_src = (int*)w;            w += (size_t)N_EDGES * 4;
    int*            bedge   = (int*)w;            w += (size_t)N_EDGES * 4;
    int*            row_ptr = (int*)w;            w += (size_t)(N_NODES + 1) * 4;
    int*            bcnt    = (int*)w;            w += (size_t)NBUCK * 4;
    int*            bbase   = (int*)w;            w += (size_t)NBUCK * 4;
    int*            gcursor = (int*)w;            w += (size_t)NBUCK * 4;
    float*          sums    = (float*)w;          w += (size_t)NB * HDIM * 4;
    float*          cnt     = (float*)w;          w += (size_t)NB * 4;
    unsigned short* whi[3];
    unsigned short* wlo[3];
    const int wsz[3] = {64 * F_IN, 64 * HDIM, 64 * HDIM};   // per-mat elems
    for (int l = 0; l < 3; l++) {
        whi[l] = (unsigned short*)w; w += (size_t)4 * wsz[l] * 2;
        wlo[l] = (unsigned short*)w; w += (size_t)4 * wsz[l] * 2;
    }

    const int gemm_gx = (N_NODES + 127) / 128;
    const int node_gx = (N_NODES + 3) / 4;
    const int pool_gx = (N_NODES + 64 * 4 - 1) / (64 * 4);

    // ----- W split to bf16 hi/lo (once) -----
    for (int l = 0; l < 3; l++) {
        int n = wsz[l];
        wsplit<<<(4 * n + 255) / 256, 256, 0, stream>>>(
            W[l][0], W[l][1], W[l][2], W[l][3], whi[l], wlo[l], n);
    }

    // ----- CSR build via LDS-staged counting sort (once; shared by all layers) -----
    hipMemsetAsync(bcnt, 0, (size_t)NBUCK * 4, stream);
    count_bucket<<<EW_GRID, 256, 0, stream>>>(ei, bcnt);
    scan_bucket<<<1, 256, 0, stream>>>(bcnt, bbase, gcursor);
    bucket_scatter<<<EW_GRID, 256, 0, stream>>>(ei, gcursor, bedge);
    csr_from_buckets<<<NBUCK, 256, 0, stream>>>(bedge, bbase, bcnt, row_ptr, csr_src);

    for (int l = 0; l < 3; l++) {
        if (l == 0) {
            qkvs_gemm_mfma<F_IN><<<dim3(gemm_gx, 2), 256, 0, stream>>>(
                x, whi[0], wlo[0], B[0][0], B[0][1], B[0][2], B[0][3],
                q, k16, v16, skip);
        } else {
            qkvs_gemm_mfma<HDIM><<<dim3(gemm_gx, 2), 256, 0, stream>>>(
                h, whi[l], wlo[l], B[l][0], B[l][1], B[l][2], B[l][3],
                q, k16, v16, skip);
        }
        attn_fused<<<node_gx, 256, 0, stream>>>(
            row_ptr, csr_src, q, k16, v16, skip, h, l < 2 ? 1 : 0);
    }

    hipMemsetAsync(sums, 0, (size_t)NB * HDIM * 4, stream);
    hipMemsetAsync(cnt,  0, (size_t)NB * 4, stream);
    pool_kernel<<<pool_gx, 256, 0, stream>>>(h, batch, sums, cnt);
    head_kernel<<<1, 640, 0, stream>>>(sums, cnt, Wl, bl, out);
}

// Round 16
// 484.871 us; speedup vs baseline: 1.1789x; 1.0079x over previous
//
#include <hip/hip_runtime.h>
#include <math.h>

#define N_NODES 100000
#define N_EDGES 1600000
#define NB 64
#define F_IN 128
#define HDIM 64
#define NC 10

#define BSHIFT 9
#define BUCKET_NODES (1 << BSHIFT)                          // 512
#define NBUCK ((N_NODES + BUCKET_NODES - 1) >> BSHIFT)      // 196
#define EW_CHUNK 4096
#define EW_GRID ((N_EDGES + EW_CHUNK - 1) / EW_CHUNK)       // 391

typedef __attribute__((ext_vector_type(8))) short bf16x8;
typedef __attribute__((ext_vector_type(4))) float f32x4;

// ---------- bf16 helpers ----------
__device__ __forceinline__ unsigned short f2bf(float f) {
    unsigned u = __float_as_uint(f);
    u += 0x7FFFu + ((u >> 16) & 1u);    // round to nearest even
    return (unsigned short)(u >> 16);
}
__device__ __forceinline__ float bf2f(unsigned short b) {
    return __uint_as_float((unsigned)b << 16);
}

// ---------- W split: W -> bf16 hi + bf16 lo (residual) ----------
__global__ __launch_bounds__(256) void wsplit(
    const float* __restrict__ W0, const float* __restrict__ W1,
    const float* __restrict__ W2, const float* __restrict__ W3,
    unsigned short* __restrict__ hi, unsigned short* __restrict__ lo, int n)
{
    int i = blockIdx.x * 256 + threadIdx.x;
    if (i >= 4 * n) return;
    const float* Ws[4] = {W0, W1, W2, W3};
    float w = Ws[i / n][i % n];
    unsigned short h = f2bf(w);
    hi[i] = h;
    lo[i] = f2bf(w - bf2f(h));
}

// ---------- fused q/k/v/skip GEMM via MFMA (bf16 3-term residual) ----------
// Wave = 32 rows (2 row-tiles). gridDim.y = 2 (2 mats per block).
// B fragments staged ONCE per block into LDS in lane-read order (1KB blocks,
// lds[bidx*1024 + lane*16]) -> compute reads are contiguous ds_read_b128,
// conflict-free; B L2 traffic drops 410 MB -> 100 MB. (r15 was latency-bound
// on per-wave 16B-granular L2 B-loads: MfmaUtil 9%, dur flat vs r13.)
template<int K>
__global__ __launch_bounds__(256) void qkvs_gemm_mfma(
    const float* __restrict__ xin,
    const unsigned short* __restrict__ whi,
    const unsigned short* __restrict__ wlo,
    const float* __restrict__ bq, const float* __restrict__ bk,
    const float* __restrict__ bv, const float* __restrict__ bs,
    float* __restrict__ q, unsigned short* __restrict__ k16,
    unsigned short* __restrict__ v16, float* __restrict__ sk)
{
    constexpr int NCH = K / 32;
    constexpr int NBB = 2 * 4 * NCH * 2;    // mats * col-tiles * chunks * (hi,lo)
    __shared__ short Blds[NBB * 512];       // 1 KB per fragment-block

    const int tid = threadIdx.x;
    const int wv  = tid >> 6;
    const int l   = tid & 63;
    const int lr  = l & 15;      // A-row / B-col / D-col within tile
    const int lg  = l >> 4;      // k-group (8 consecutive k) ; D-row group
    const int row0 = blockIdx.x * 128 + wv * 32;
    const int mat0 = blockIdx.y * 2;

    // ---- stage B fragment-blocks into LDS (each wave stages NBB/4 blocks) ----
    #pragma unroll
    for (int it = 0; it < NBB / 4; it++) {
        int bidx = it * 4 + wv;
        int hsel = bidx & 1;
        int rest = bidx >> 1;                 // (mm*4 + ct)*NCH + c
        int c    = rest & (NCH - 1);
        int q2   = rest / NCH;                // mm*4 + ct
        int ct   = q2 & 3;
        int mm   = q2 >> 2;
        const unsigned short* src = hsel ? wlo : whi;
        size_t goff = (size_t)((mat0 + mm) * 64 + ct * 16 + lr) * K + c * 32 + lg * 8;
        uint4 d = *(const uint4*)&src[goff];
        *(uint4*)&Blds[bidx * 512 + l * 8] = d;
    }

    // ---- load X rows, split into bf16 hi/lo fragments ----
    bf16x8 Ahi[2][NCH], Alo[2][NCH];
    #pragma unroll
    for (int rt = 0; rt < 2; rt++) {
        int row = row0 + rt * 16 + lr;
        bool ok = row < N_NODES;
        const float* xr = xin + (size_t)(ok ? row : 0) * K + lg * 8;
        #pragma unroll
        for (int c = 0; c < NCH; c++) {
            float4 f0, f1;
            if (ok) {
                f0 = *(const float4*)(xr + c * 32);
                f1 = *(const float4*)(xr + c * 32 + 4);
            } else {
                f0 = make_float4(0.f, 0.f, 0.f, 0.f);
                f1 = f0;
            }
            float xv[8] = {f0.x, f0.y, f0.z, f0.w, f1.x, f1.y, f1.z, f1.w};
            #pragma unroll
            for (int j = 0; j < 8; j++) {
                unsigned short hb = f2bf(xv[j]);
                Ahi[rt][c][j] = (short)hb;
                Alo[rt][c][j] = (short)f2bf(xv[j] - bf2f(hb));
            }
        }
    }

    __syncthreads();   // B staged

    const float* Bm[4] = {bq, bk, bv, bs};

    #pragma unroll
    for (int mm = 0; mm < 2; mm++) {
        const int mat = mat0 + mm;
        #pragma unroll
        for (int ct = 0; ct < 4; ct++) {
            f32x4 acc0 = {0.f, 0.f, 0.f, 0.f};
            f32x4 acc1 = {0.f, 0.f, 0.f, 0.f};
            #pragma unroll
            for (int c = 0; c < NCH; c++) {
                const int bb = ((mm * 4 + ct) * NCH + c) << 1;
                bf16x8 Bhi = *(const bf16x8*)&Blds[bb * 512 + l * 8];
                bf16x8 Blo = *(const bf16x8*)&Blds[(bb + 1) * 512 + l * 8];
                acc0 = __builtin_amdgcn_mfma_f32_16x16x32_bf16(Ahi[0][c], Bhi, acc0, 0, 0, 0);
                acc1 = __builtin_amdgcn_mfma_f32_16x16x32_bf16(Ahi[1][c], Bhi, acc1, 0, 0, 0);
                acc0 = __builtin_amdgcn_mfma_f32_16x16x32_bf16(Alo[0][c], Bhi, acc0, 0, 0, 0);
                acc1 = __builtin_amdgcn_mfma_f32_16x16x32_bf16(Alo[1][c], Bhi, acc1, 0, 0, 0);
                acc0 = __builtin_amdgcn_mfma_f32_16x16x32_bf16(Ahi[0][c], Blo, acc0, 0, 0, 0);
                acc1 = __builtin_amdgcn_mfma_f32_16x16x32_bf16(Ahi[1][c], Blo, acc1, 0, 0, 0);
            }
            float bias = Bm[mat][ct * 16 + lr];
            int colo = ct * 16 + lr;
            // D layout: row = rt*16 + lg*4 + i, col = lr (within tile)
            #pragma unroll
            for (int i = 0; i < 4; i++) {
                int row = row0 + lg * 4 + i;
                if (row < N_NODES) {
                    float val = acc0[i] + bias;
                    size_t off = (size_t)row * HDIM + colo;
                    if (mat == 0)      q[off]   = val;
                    else if (mat == 1) k16[off] = f2bf(val);
                    else if (mat == 2) v16[off] = f2bf(val);
                    else               sk[off]  = val;
                }
            }
            #pragma unroll
            for (int i = 0; i < 4; i++) {
                int row = row0 + 16 + lg * 4 + i;
                if (row < N_NODES) {
                    float val = acc1[i] + bias;
                    size_t off = (size_t)row * HDIM + colo;
                    if (mat == 0)      q[off]   = val;
                    else if (mat == 1) k16[off] = f2bf(val);
                    else if (mat == 2) v16[off] = f2bf(val);
                    else               sk[off]  = val;
                }
            }
        }
    }
}

// ---------- CSR build, stage 1: per-bucket edge counts (LDS hist only) ----------
__global__ __launch_bounds__(256) void count_bucket(
    const int* __restrict__ ei, int* __restrict__ bcnt)
{
    __shared__ int hist[NBUCK];
    for (int i = threadIdx.x; i < NBUCK; i += 256) hist[i] = 0;
    __syncthreads();
    int e0 = blockIdx.x * EW_CHUNK;
    #pragma unroll
    for (int i = 0; i < EW_CHUNK / 256; i++) {
        int e = e0 + i * 256 + threadIdx.x;
        if (e < N_EDGES) atomicAdd(&hist[ei[N_EDGES + e] >> BSHIFT], 1);
    }
    __syncthreads();
    for (int i = threadIdx.x; i < NBUCK; i += 256)
        if (hist[i]) atomicAdd(&bcnt[i], hist[i]);
}

// ---------- CSR build, stage 2: bucket base scan (196 values, one block) ----------
__global__ __launch_bounds__(256) void scan_bucket(
    const int* __restrict__ bcnt, int* __restrict__ bbase, int* __restrict__ gcursor)
{
    __shared__ int sh[256];
    int t = threadIdx.x;
    int v = (t < NBUCK) ? bcnt[t] : 0;
    sh[t] = v;
    __syncthreads();
    for (int off = 1; off < 256; off <<= 1) {
        int u = (t >= off) ? sh[t - off] : 0;
        __syncthreads();
        sh[t] += u;
        __syncthreads();
    }
    if (t < NBUCK) { bbase[t] = sh[t] - v; gcursor[t] = sh[t] - v; }
}

// ---------- CSR build, stage 3: scatter packed edges into bucket order ----------
// packed entry: (dst_local << 17) | src
__global__ __launch_bounds__(256) void bucket_scatter(
    const int* __restrict__ ei, int* __restrict__ gcursor, int* __restrict__ bedge)
{
    __shared__ int hist[NBUCK];
    __shared__ int base[NBUCK];
    for (int i = threadIdx.x; i < NBUCK; i += 256) hist[i] = 0;
    __syncthreads();
    int e0 = blockIdx.x * EW_CHUNK;
    #pragma unroll
    for (int i = 0; i < EW_CHUNK / 256; i++) {
        int e = e0 + i * 256 + threadIdx.x;
        if (e < N_EDGES) atomicAdd(&hist[ei[N_EDGES + e] >> BSHIFT], 1);
    }
    __syncthreads();
    for (int i = threadIdx.x; i < NBUCK; i += 256)
        base[i] = hist[i] ? atomicAdd(&gcursor[i], hist[i]) : 0;
    __syncthreads();
    for (int i = threadIdx.x; i < NBUCK; i += 256) hist[i] = 0;
    __syncthreads();
    #pragma unroll
    for (int i = 0; i < EW_CHUNK / 256; i++) {
        int e = e0 + i * 256 + threadIdx.x;
        if (e < N_EDGES) {
            int src = ei[e];
            int dst = ei[N_EDGES + e];
            int b = dst >> BSHIFT;
            int pos = base[b] + atomicAdd(&hist[b], 1);
            bedge[pos] = ((dst & (BUCKET_NODES - 1)) << 17) | src;
        }
    }
}

// ---------- CSR build, stage 4: one WG per bucket ----------
__global__ __launch_bounds__(256) void csr_from_buckets(
    const int* __restrict__ bedge, const int* __restrict__ bbase,
    const int* __restrict__ bcnt, int* __restrict__ row_ptr,
    int* __restrict__ csr_src)
{
    __shared__ int cur[BUCKET_NODES];   // 512
    __shared__ int psum[256];
    const int b = blockIdx.x;
    const int dst0 = b << BSHIFT;
    const int t = threadIdx.x;

    for (int i = t; i < BUCKET_NODES; i += 256) cur[i] = 0;
    __syncthreads();

    const int beg = bbase[b], cnt = bcnt[b];
    for (int i = t; i < cnt; i += 256)
        atomicAdd(&cur[bedge[beg + i] >> 17], 1);
    __syncthreads();

    int a0 = cur[2 * t], a1 = cur[2 * t + 1];
    int pair = a0 + a1;
    psum[t] = pair;
    __syncthreads();
    for (int off = 1; off < 256; off <<= 1) {
        int u = (t >= off) ? psum[t - off] : 0;
        __syncthreads();
        psum[t] += u;
        __syncthreads();
    }
    int ex = psum[t] - pair;            // exclusive prefix of this pair

    int d0 = dst0 + 2 * t, d1 = d0 + 1;
    int g0 = beg + ex, g1 = beg + ex + a0;
    if (d0 < N_NODES) row_ptr[d0] = g0;
    if (d1 < N_NODES) row_ptr[d1] = g1;
    if (b == gridDim.x - 1 && t == 255) row_ptr[N_NODES] = beg + psum[255];
    cur[2 * t] = g0;
    cur[2 * t + 1] = g1;
    __syncthreads();

    for (int i = t; i < cnt; i += 256) {
        int ed = bedge[beg + i];
        int pos = atomicAdd(&cur[ed >> 17], 1);
        csr_src[pos] = ed & 0x1FFFF;
    }
}

// ---------- fused attention: wave per dst, 8 edges/iter, bf16 k/v gathers ----------
__global__ __launch_bounds__(256) void attn_fused(
    const int* __restrict__ row_ptr, const int* __restrict__ csr_src,
    const float* __restrict__ q, const unsigned short* __restrict__ k16,
    const unsigned short* __restrict__ v16, const float* __restrict__ skip,
    float* __restrict__ hout, int do_relu)
{
    int n = blockIdx.x * 4 + (threadIdx.x >> 6);
    if (n >= N_NODES) return;
    int lane = threadIdx.x & 63;
    int g = lane >> 3;
    int t = lane & 7;
    int beg = row_ptr[n], end = row_ptr[n + 1];

    const float* qrow = &q[(size_t)n * HDIM + t * 8];
    float4 qa = *(const float4*)qrow;
    float4 qb = *(const float4*)(qrow + 4);
    float m = -1e30f, s = 0.f;
    float4 aca = make_float4(0.f, 0.f, 0.f, 0.f);
    float4 acb = make_float4(0.f, 0.f, 0.f, 0.f);

    for (int i = beg; i < end; i += 8) {
        int e = i + g;
        bool valid = (e < end);
        int src = csr_src[valid ? e : beg];
        uint4 ku = *(const uint4*)&k16[(size_t)src * HDIM + t * 8];
        uint4 vu = *(const uint4*)&v16[(size_t)src * HDIM + t * 8];
        float p = qa.x * __uint_as_float(ku.x << 16)
                + qa.y * __uint_as_float(ku.x & 0xFFFF0000u)
                + qa.z * __uint_as_float(ku.y << 16)
                + qa.w * __uint_as_float(ku.y & 0xFFFF0000u)
                + qb.x * __uint_as_float(ku.z << 16)
                + qb.y * __uint_as_float(ku.z & 0xFFFF0000u)
                + qb.z * __uint_as_float(ku.w << 16)
                + qb.w * __uint_as_float(ku.w & 0xFFFF0000u);
        p += __shfl_xor(p, 1, 64);
        p += __shfl_xor(p, 2, 64);
        p += __shfl_xor(p, 4, 64);
        float a = valid ? p * 0.125f : -INFINITY;
        float mn = fmaxf(m, a);
        float sc = __expf(m - mn);
        float ew = __expf(a - mn);
        s = s * sc + ew;
        aca.x = aca.x * sc + ew * __uint_as_float(vu.x << 16);
        aca.y = aca.y * sc + ew * __uint_as_float(vu.x & 0xFFFF0000u);
        aca.z = aca.z * sc + ew * __uint_as_float(vu.y << 16);
        aca.w = aca.w * sc + ew * __uint_as_float(vu.y & 0xFFFF0000u);
        acb.x = acb.x * sc + ew * __uint_as_float(vu.z << 16);
        acb.y = acb.y * sc + ew * __uint_as_float(vu.z & 0xFFFF0000u);
        acb.z = acb.z * sc + ew * __uint_as_float(vu.w << 16);
        acb.w = acb.w * sc + ew * __uint_as_float(vu.w & 0xFFFF0000u);
        m = mn;
    }

    #pragma unroll
    for (int off = 8; off <= 32; off <<= 1) {
        float m2 = __shfl_xor(m, off, 64);
        float s2 = __shfl_xor(s, off, 64);
        float x0 = __shfl_xor(aca.x, off, 64);
        float x1 = __shfl_xor(aca.y, off, 64);
        float x2 = __shfl_xor(aca.z, off, 64);
        float x3 = __shfl_xor(aca.w, off, 64);
        float x4 = __shfl_xor(acb.x, off, 64);
        float x5 = __shfl_xor(acb.y, off, 64);
        float x6 = __shfl_xor(acb.z, off, 64);
        float x7 = __shfl_xor(acb.w, off, 64);
        float mn = fmaxf(m, m2);
        float c1 = __expf(m - mn);
        float c2 = __expf(m2 - mn);
        s = s * c1 + s2 * c2;
        aca.x = aca.x * c1 + x0 * c2;
        aca.y = aca.y * c1 + x1 * c2;
        aca.z = aca.z * c1 + x2 * c2;
        aca.w = aca.w * c1 + x3 * c2;
        acb.x = acb.x * c1 + x4 * c2;
        acb.y = acb.y * c1 + x5 * c2;
        acb.z = acb.z * c1 + x6 * c2;
        acb.w = acb.w * c1 + x7 * c2;
        m = mn;
    }

    if (g == 0) {
        float inv = (s > 0.f) ? (1.f / s) : 0.f;
        const float* skrow = &skip[(size_t)n * HDIM + t * 8];
        float4 s0 = *(const float4*)skrow;
        float4 s1 = *(const float4*)(skrow + 4);
        float4 o0, o1;
        o0.x = aca.x * inv + s0.x;
        o0.y = aca.y * inv + s0.y;
        o0.z = aca.z * inv + s0.z;
        o0.w = aca.w * inv + s0.w;
        o1.x = acb.x * inv + s1.x;
        o1.y = acb.y * inv + s1.y;
        o1.z = acb.z * inv + s1.z;
        o1.w = acb.w * inv + s1.w;
        if (do_relu) {
            o0.x = fmaxf(o0.x, 0.f); o0.y = fmaxf(o0.y, 0.f);
            o0.z = fmaxf(o0.z, 0.f); o0.w = fmaxf(o0.w, 0.f);
            o1.x = fmaxf(o1.x, 0.f); o1.y = fmaxf(o1.y, 0.f);
            o1.z = fmaxf(o1.z, 0.f); o1.w = fmaxf(o1.w, 0.f);
        }
        float* orow = &hout[(size_t)n * HDIM + t * 8];
        *(float4*)orow = o0;
        *(float4*)(orow + 4) = o1;
    }
}

// ---------- mean pool: run-length accumulate (batch sorted) ----------
__global__ __launch_bounds__(256) void pool_kernel(
    const float* __restrict__ h, const int* __restrict__ batch,
    float* __restrict__ sums, float* __restrict__ cnt)
{
    int wid = blockIdx.x * 4 + (threadIdx.x >> 6);
    int n0 = wid * 64;
    if (n0 >= N_NODES) return;
    int lane = threadIdx.x & 63;
    int nend = min(n0 + 64, N_NODES);
    float acc = 0.f;
    int b_cur = batch[n0];
    int run = 0;
    for (int n = n0; n < nend; n++) {
        int b = batch[n];
        if (b != b_cur) {
            atomicAdd(&sums[b_cur * HDIM + lane], acc);
            if (lane == 0) atomicAdd(&cnt[b_cur], (float)run);
            acc = 0.f; run = 0; b_cur = b;
        }
        acc += h[(size_t)n * HDIM + lane];
        run++;
    }
    atomicAdd(&sums[b_cur * HDIM + lane], acc);
    if (lane == 0) atomicAdd(&cnt[b_cur], (float)run);
}

// ---------- head ----------
__global__ void head_kernel(
    const float* __restrict__ sums, const float* __restrict__ cnt,
    const float* __restrict__ Wl, const float* __restrict__ bl,
    float* __restrict__ out)
{
    int tid = threadIdx.x;
    if (tid >= NB * NC) return;
    int b = tid / NC, c = tid % NC;
    float cc = fmaxf(cnt[b], 1.0f);
    float acc = bl[c];
    #pragma unroll
    for (int f = 0; f < HDIM; f++)
        acc += (sums[b * HDIM + f] / cc) * Wl[c * HDIM + f];
    out[tid] = acc;
}

extern "C" void kernel_launch(void* const* d_in, const int* in_sizes, int n_in,
                              void* d_out, int out_size, void* d_ws, size_t ws_size,
                              hipStream_t stream)
{
    const float* x     = (const float*)d_in[0];
    const int*   ei    = (const int*)d_in[1];
    const int*   batch = (const int*)d_in[2];

    const float* W[3][4];
    const float* B[3][4];
    for (int l = 0; l < 3; l++)
        for (int j = 0; j < 4; j++) {
            W[l][j] = (const float*)d_in[3 + l * 8 + j * 2];
            B[l][j] = (const float*)d_in[3 + l * 8 + j * 2 + 1];
        }
    const float* Wl = (const float*)d_in[27];
    const float* bl = (const float*)d_in[28];
    float* out = (float*)d_out;

    const size_t NF = (size_t)N_NODES * HDIM;
    char* w = (char*)d_ws;
    float*          h       = (float*)w;          w += NF * 4;
    float*          q       = (float*)w;          w += NF * 4;
    unsigned short* k16     = (unsigned short*)w; w += NF * 2;
    unsigned short* v16     = (unsigned short*)w; w += NF * 2;
    float*          skip    = (float*)w;          w += NF * 4;
    int*            csr_src = (int*)w;            w += (size_t)N_EDGES * 4;
    int*            bedge   = (int*)w;            w += (size_t)N_EDGES * 4;
    int*            row_ptr = (int*)w;            w += (size_t)(N_NODES + 1) * 4;
    int*            bcnt    = (int*)w;            w += (size_t)NBUCK * 4;
    int*            bbase   = (int*)w;            w += (size_t)NBUCK * 4;
    int*            gcursor = (int*)w;            w += (size_t)NBUCK * 4;
    float*          sums    = (float*)w;          w += (size_t)NB * HDIM * 4;
    float*          cnt     = (float*)w;          w += (size_t)NB * 4;
    unsigned short* whi[3];
    unsigned short* wlo[3];
    const int wsz[3] = {64 * F_IN, 64 * HDIM, 64 * HDIM};   // per-mat elems
    for (int l = 0; l < 3; l++) {
        whi[l] = (unsigned short*)w; w += (size_t)4 * wsz[l] * 2;
        wlo[l] = (unsigned short*)w; w += (size_t)4 * wsz[l] * 2;
    }

    const int gemm_gx = (N_NODES + 127) / 128;
    const int node_gx = (N_NODES + 3) / 4;
    const int pool_gx = (N_NODES + 64 * 4 - 1) / (64 * 4);

    // ----- W split to bf16 hi/lo (once) -----
    for (int l = 0; l < 3; l++) {
        int n = wsz[l];
        wsplit<<<(4 * n + 255) / 256, 256, 0, stream>>>(
            W[l][0], W[l][1], W[l][2], W[l][3], whi[l], wlo[l], n);
    }

    // ----- CSR build via LDS-staged counting sort (once; shared by all layers) -----
    hipMemsetAsync(bcnt, 0, (size_t)NBUCK * 4, stream);
    count_bucket<<<EW_GRID, 256, 0, stream>>>(ei, bcnt);
    scan_bucket<<<1, 256, 0, stream>>>(bcnt, bbase, gcursor);
    bucket_scatter<<<EW_GRID, 256, 0, stream>>>(ei, gcursor, bedge);
    csr_from_buckets<<<NBUCK, 256, 0, stream>>>(bedge, bbase, bcnt, row_ptr, csr_src);

    for (int l = 0; l < 3; l++) {
        if (l == 0) {
            qkvs_gemm_mfma<F_IN><<<dim3(gemm_gx, 2), 256, 0, stream>>>(
                x, whi[0], wlo[0], B[0][0], B[0][1], B[0][2], B[0][3],
                q, k16, v16, skip);
        } else {
            qkvs_gemm_mfma<HDIM><<<dim3(gemm_gx, 2), 256, 0, stream>>>(
                h, whi[l], wlo[l], B[l][0], B[l][1], B[l][2], B[l][3],
                q, k16, v16, skip);
        }
        attn_fused<<<node_gx, 256, 0, stream>>>(
            row_ptr, csr_src, q, k16, v16, skip, h, l < 2 ? 1 : 0);
    }

    hipMemsetAsync(sums, 0, (size_t)NB * HDIM * 4, stream);
    hipMemsetAsync(cnt,  0, (size_t)NB * 4, stream);
    pool_kernel<<<pool_gx, 256, 0, stream>>>(h, batch, sums, cnt);
    head_kernel<<<1, 640, 0, stream>>>(sums, cnt, Wl, bl, out);
}